// Round 7
// baseline (479.530 us; speedup 1.0000x reference)
//
#include <hip/hip_runtime.h>

#define NSEQ   4096
#define TSTEPS 512
#define FIN    5
#define HID    64
#define SPB    16     // sequences per block (MFMA M)
#define BLK    512    // 8 waves: wave w and w+4 pair on identical MFMAs,
                      // split epilogue rows -> 2 waves/SIMD latency hiding

// Neutral names — do NOT reuse HIP vector-type names like short8 (R4 crash)
typedef __attribute__((ext_vector_type(8))) short bsh8;    // 8 bf16 in 4 VGPRs
typedef __attribute__((ext_vector_type(4))) float f32x4;   // MFMA accumulator

#define MFMA16(A, B, C) __builtin_amdgcn_mfma_f32_16x16x32_bf16((A), (B), (C), 0, 0, 0)

struct Frag2 { bsh8 hi; bsh8 lo; };

__device__ __forceinline__ unsigned short bf16hi_rn(float x) {
    unsigned u = __float_as_uint(x);
    return (unsigned short)((u + 0x7fffu + ((u >> 16) & 1u)) >> 16);
}
__device__ __forceinline__ void split_bf16(float v, unsigned short& h, unsigned short& l) {
    h = bf16hi_rn(v);
    float hf = __uint_as_float(((unsigned)h) << 16);
    l = bf16hi_rn(v - hf);
}

__device__ __forceinline__ float fast_sigmoid(float x) {
    return __builtin_amdgcn_rcpf(1.0f + __expf(-x));
}
__device__ __forceinline__ float fast_tanh(float x) {
    return 1.0f - 2.0f * __builtin_amdgcn_rcpf(1.0f + __expf(2.0f * x));
}

// B-fragment (weights SPLIT hi/lo — systematic weight error stays ~2^-17)
__device__ __forceinline__ Frag2 load_whh_frag(const float* __restrict__ Whh, int gate, int k) {
    const float* p = Whh + gate * HID + k;
    Frag2 r;
#pragma unroll
    for (int j = 0; j < 8; ++j) {
        unsigned short h, l;
        split_bf16(p[j], h, l);
        r.hi[j] = (short)h; r.lo[j] = (short)l;
    }
    return r;
}
__device__ __forceinline__ Frag2 load_wih_frag(const float* __restrict__ Wih, int gate, int quad) {
    Frag2 r;
#pragma unroll
    for (int j = 0; j < 8; ++j) { r.hi[j] = 0; r.lo[j] = 0; }
    if (quad == 0) {
#pragma unroll
        for (int j = 0; j < FIN; ++j) {
            unsigned short h, l;
            split_bf16(Wih[gate * FIN + j], h, l);
            r.hi[j] = (short)h; r.lo[j] = (short)l;
        }
    }
    return r;
}

// stage one 64-step x chunk (bf16-hi) into dst[64][SPB]
__device__ __forceinline__ void stage_chunk(const float* __restrict__ feat,
                                            bsh8 (*dst)[SPB],
                                            int seq0, int t0, int tid) {
#pragma unroll
    for (int it = 0; it < (64 * SPB) / BLK; ++it) {
        int idx = tid + it * BLK;
        int t2  = idx >> 4;
        int s   = idx & 15;
        const float* xp = feat + (size_t)(seq0 + s) * (TSTEPS * FIN) + (t0 + t2) * FIN;
        bsh8 v = {0, 0, 0, 0, 0, 0, 0, 0};
#pragma unroll
        for (int j = 0; j < FIN; ++j) v[j] = (short)bf16hi_rn(xp[j]);
        dst[t2][s] = v;
    }
}

// MFMA LSTM, A plain bf16, weights split hi/lo. 8 waves: waves w and w+4
// duplicate the same 24 MFMA/step (no communication), then each activates 2
// of the 4 C-rows -> per-wave transcendental count halves and 2 waves/SIMD
// hide each other's ds_read/trans/MFMA latencies (R6 was 1 wave/SIMD: ~600
// stall cyc/step exposed). One barrier per step. Fused pred head in tail.
__global__ __launch_bounds__(BLK)
void lstm_kernel(const float* __restrict__ feat,
                 const float* __restrict__ Wih,
                 const float* __restrict__ Whh,
                 const float* __restrict__ bih,
                 const float* __restrict__ bhh,
                 const float* __restrict__ Wd,
                 const float* __restrict__ bd,
                 float* __restrict__ pred,
                 float* __restrict__ accums) {
    __shared__ bsh8  aA[2][SPB][9];     // h bf16-hi, double-buffered; pitch 9 vecs
    __shared__ bsh8  xb[2][64][SPB];    // x bf16-hi, chunk double buffer (32 KB)
    __shared__ float hf[SPB][HID + 1];  // final h fp32 for pred tail
    __shared__ float pf[SPB][17];       // pred partials

    const int tid   = threadIdx.x;
    const int w     = tid >> 6;         // wave 0..7
    const int lane  = tid & 63;
    const int col   = lane & 15;        // MFMA col / A-row (seq)
    const int quad  = lane >> 4;
    const int u     = 16 * (w & 3) + col;   // unit handled by this lane (pairs share)
    const int rbase = (w >> 2) * 2;     // waves 0-3: rows 0,1; waves 4-7: rows 2,3
    const int seq0  = blockIdx.x * SPB;

    if (blockIdx.x == 0 && tid < 4) accums[tid] = 0.0f;   // loss accumulators

    // ---- persistent B fragments (named structs — R1/R2 spill lessons) ----
    const int g0 = 0 * HID + u, g1 = 1 * HID + u, g2 = 2 * HID + u, g3 = 3 * HID + u;
    Frag2 b00 = load_whh_frag(Whh, g0, quad * 8);
    Frag2 b01 = load_whh_frag(Whh, g0, 32 + quad * 8);
    Frag2 b02 = load_wih_frag(Wih, g0, quad);
    Frag2 b10 = load_whh_frag(Whh, g1, quad * 8);
    Frag2 b11 = load_whh_frag(Whh, g1, 32 + quad * 8);
    Frag2 b12 = load_wih_frag(Wih, g1, quad);
    Frag2 b20 = load_whh_frag(Whh, g2, quad * 8);
    Frag2 b21 = load_whh_frag(Whh, g2, 32 + quad * 8);
    Frag2 b22 = load_wih_frag(Wih, g2, quad);
    Frag2 b30 = load_whh_frag(Whh, g3, quad * 8);
    Frag2 b31 = load_whh_frag(Whh, g3, 32 + quad * 8);
    Frag2 b32 = load_wih_frag(Wih, g3, quad);

    const float bi  = bih[g0] + bhh[g0];
    const float bf_ = bih[g1] + bhh[g1];
    const float bg  = bih[g2] + bhh[g2];
    const float bo  = bih[g3] + bhh[g3];

    // zero h buffer 0 (144 vectors)
    {
        bsh8 z = {0, 0, 0, 0, 0, 0, 0, 0};
        if (tid < SPB * 9) (&aA[0][0][0])[tid] = z;
    }
    stage_chunk(feat, xb[0], seq0, 0, tid);
    __syncthreads();

    // acc := bias + x-part of step 0 (8 MFMAs, duplicated across wave pairs)
    f32x4 acc0 = {bi,  bi,  bi,  bi };
    f32x4 acc1 = {bf_, bf_, bf_, bf_};
    f32x4 acc2 = {bg,  bg,  bg,  bg };
    f32x4 acc3 = {bo,  bo,  bo,  bo };
    {
        bsh8 ax = xb[0][0][col];
        acc0 = MFMA16(ax, b02.hi, acc0); acc0 = MFMA16(ax, b02.lo, acc0);
        acc1 = MFMA16(ax, b12.hi, acc1); acc1 = MFMA16(ax, b12.lo, acc1);
        acc2 = MFMA16(ax, b22.hi, acc2); acc2 = MFMA16(ax, b22.lo, acc2);
        acc3 = MFMA16(ax, b32.hi, acc3); acc3 = MFMA16(ax, b32.lo, acc3);
    }

    float c_[2] = {0.f, 0.f};   // this wave's 2 rows

    for (int t = 0; t < TSTEPS; ++t) {
        const int tt  = t & 63;
        const int buf = t & 1;
        const int nb  = buf ^ 1;
        __syncthreads();   // h(t-1) writes + staged x visible

        // prefetch-stage next chunk (buffer has been idle 64 steps)
        if (tt == 0 && t + 64 < TSTEPS) {
            int nc = (t >> 6) + 1;
            stage_chunk(feat, xb[nc & 1], seq0, nc * 64, tid);
        }

        // ---- 16 h-MFMAs (critical path; duplicated across wave pairs) ----
        bsh8 ah0 = aA[buf][col][quad];
        bsh8 ah1 = aA[buf][col][4 + quad];
        acc0 = MFMA16(ah0, b00.hi, acc0); acc0 = MFMA16(ah1, b01.hi, acc0);
        acc1 = MFMA16(ah0, b10.hi, acc1); acc1 = MFMA16(ah1, b11.hi, acc1);
        acc2 = MFMA16(ah0, b20.hi, acc2); acc2 = MFMA16(ah1, b21.hi, acc2);
        acc3 = MFMA16(ah0, b30.hi, acc3); acc3 = MFMA16(ah1, b31.hi, acc3);
        acc0 = MFMA16(ah0, b00.lo, acc0); acc0 = MFMA16(ah1, b01.lo, acc0);
        acc1 = MFMA16(ah0, b10.lo, acc1); acc1 = MFMA16(ah1, b11.lo, acc1);
        acc2 = MFMA16(ah0, b20.lo, acc2); acc2 = MFMA16(ah1, b21.lo, acc2);
        acc3 = MFMA16(ah0, b30.lo, acc3); acc3 = MFMA16(ah1, b31.lo, acc3);

        // ---- epilogue: this wave's 2 rows (seq = quad*4 + rbase + r2) ----
#pragma unroll
        for (int r2 = 0; r2 < 2; ++r2) {
            const int r = rbase + r2;
            float gi = fast_sigmoid(acc0[r]);
            float gf = fast_sigmoid(acc1[r]);
            float gg = fast_tanh  (acc2[r]);
            float go = fast_sigmoid(acc3[r]);
            c_[r2] = gf * c_[r2] + gi * gg;
            float hh = go * fast_tanh(c_[r2]);
            int seqr = quad * 4 + r;
            ((unsigned short*)&aA[nb][seqr][0])[u] = bf16hi_rn(hh);
            if (t == TSTEPS - 1) hf[seqr][u] = hh;
        }

        // ---- x-part of step t+1 (off critical path; before next barrier) ----
        if (t < TSTEPS - 1) {
            int t1 = t + 1;
            bsh8 ax = xb[(t1 >> 6) & 1][t1 & 63][col];
            acc0 = (f32x4){bi,  bi,  bi,  bi };
            acc1 = (f32x4){bf_, bf_, bf_, bf_};
            acc2 = (f32x4){bg,  bg,  bg,  bg };
            acc3 = (f32x4){bo,  bo,  bo,  bo };
            acc0 = MFMA16(ax, b02.hi, acc0); acc0 = MFMA16(ax, b02.lo, acc0);
            acc1 = MFMA16(ax, b12.hi, acc1); acc1 = MFMA16(ax, b12.lo, acc1);
            acc2 = MFMA16(ax, b22.hi, acc2); acc2 = MFMA16(ax, b22.lo, acc2);
            acc3 = MFMA16(ax, b32.hi, acc3); acc3 = MFMA16(ax, b32.lo, acc3);
        }
    }
    __syncthreads();   // hf visible

    // ---- fused pred head: pred = leaky_relu(h @ Wd^T + bd) ----
    if (tid < 256) {
        int s  = tid & 15;
        int q4 = tid >> 4;           // 16 unit-groups of 4
        int j0 = q4 * 4;
        float part = hf[s][j0] * Wd[j0] + hf[s][j0 + 1] * Wd[j0 + 1]
                   + hf[s][j0 + 2] * Wd[j0 + 2] + hf[s][j0 + 3] * Wd[j0 + 3];
        pf[s][q4] = part;
    }
    __syncthreads();
    if (tid < SPB) {
        float sum = bd[0];
#pragma unroll
        for (int j = 0; j < 16; ++j) sum += pf[tid][j];
        float p = (sum >= 0.0f) ? sum : 0.2f * sum;
        pred[seq0 + tid] = p;
    }
}

// fused losses: every block does a 16-i rank slice; block 0 also does reg MSE
__global__ __launch_bounds__(256)
void loss_kernel(const float* __restrict__ pred,
                 const float* __restrict__ ret,
                 const int* __restrict__ mask,
                 float* __restrict__ accums) {
    __shared__ float sp[NSEQ];
    __shared__ float sg[NSEQ];
    __shared__ float sq[NSEQ];
    int tid = threadIdx.x;
    for (int idx = tid; idx < NSEQ; idx += 256) {
        sp[idx] = pred[idx];
        sg[idx] = ret[idx];
        sq[idx] = (mask[idx] != 0) ? 1.0f : 0.0f;
    }
    __syncthreads();

    if (blockIdx.x == 0) {   // regression loss partials
        float v = 0.0f, m = 0.0f;
        for (int j = tid; j < NSEQ; j += 256) {
            float mj = sq[j];
            float d  = sp[j] - sg[j];
            v += d * d * mj;
            m += mj;
        }
#pragma unroll
        for (int off = 32; off > 0; off >>= 1) {
            v += __shfl_down(v, off, 64);
            m += __shfl_down(m, off, 64);
        }
        if ((tid & 63) == 0) {
            atomicAdd(&accums[0], v);
            atomicAdd(&accums[1], m);
        }
    }

    int iloc = tid >> 4;
    int jp   = tid & 15;
    int i    = blockIdx.x * 16 + iloc;
    float pi = sp[i], gi = sg[i], qi = sq[i];
    float sum = 0.0f;
    for (int j = jp; j < NSEQ; j += 16) {
        float t = -(sp[j] - pi) * (sg[j] - gi);
        sum += fmaxf(t, 0.0f) * sq[j];
    }
    sum *= qi;
#pragma unroll
    for (int off = 32; off > 0; off >>= 1) sum += __shfl_down(sum, off, 64);
    __shared__ float wsum[4];
    if ((tid & 63) == 0) wsum[tid >> 6] = sum;
    __syncthreads();
    if (tid == 0) atomicAdd(&accums[2], wsum[0] + wsum[1] + wsum[2] + wsum[3]);
}

__global__ void final_kernel(const float* __restrict__ accums,
                             float* __restrict__ out) {
    float reg  = accums[0] / (accums[1] + 1e-8f);
    float rank = accums[2] / 16777216.0f;   // N*N
    out[NSEQ + 0] = reg + rank;
    out[NSEQ + 1] = reg;
    out[NSEQ + 2] = rank;
}

extern "C" void kernel_launch(void* const* d_in, const int* in_sizes, int n_in,
                              void* d_out, int out_size, void* d_ws, size_t ws_size,
                              hipStream_t stream) {
    const float* feat = (const float*)d_in[0];
    const float* ret  = (const float*)d_in[1];
    const int*   mask = (const int*)d_in[2];
    const float* Wih  = (const float*)d_in[3];
    const float* Whh  = (const float*)d_in[4];
    const float* bih  = (const float*)d_in[5];
    const float* bhh  = (const float*)d_in[6];
    const float* Wd   = (const float*)d_in[7];
    const float* bd   = (const float*)d_in[8];
    float* out    = (float*)d_out;
    float* accums = (float*)d_ws;            // [0..3] loss partials

    lstm_kernel<<<NSEQ / SPB, BLK, 0, stream>>>(feat, Wih, Whh, bih, bhh,
                                                Wd, bd, out, accums);
    loss_kernel<<<NSEQ / 16, 256, 0, stream>>>(out, ret, mask, accums);
    final_kernel<<<1, 1, 0, stream>>>(accums, out);
}